// Round 14
// baseline (183.750 us; speedup 1.0000x reference)
//
#include <hip/hip_runtime.h>
#include <hip/hip_bf16.h>

// Sggnn_gcn — fused 2x(Linear512+BN+LReLU) + Wc projection, then GCN on 2-wide
// features. Restructuring: (w_norm^T @ t) @ Wc^T == w_norm^T @ (t @ Wc^T).
// v14: TWO m97-regime GEMM kernels (4-wave 256-thread blocks, 3 blocks/CU via
// __launch_bounds__(256,3) -> independent blocks hide each other's stalls;
// v9-v13's 16-wave lockstep could not). Layer-1 writes T1 in FRAGMENT-MAJOR
// global layout (coalesced) so layer-2's K-loop is barrier-free with both
// operands loaded fragment-major global->reg.

typedef __hip_bfloat16 bf16_t;
typedef __bf16 bf16x8 __attribute__((ext_vector_type(8)));
typedef __bf16 bf16x4 __attribute__((ext_vector_type(4)));
typedef float f32x4 __attribute__((ext_vector_type(4)));

#define KDIM 512

__device__ __forceinline__ float ldsel(const void* p, int i, int isbf) {
    return isbf ? __bfloat162float(((const bf16_t*)p)[i]) : ((const float*)p)[i];
}

// ---- probe: detect dtype of d (bf16 vs f32) from exponent statistics ----
__global__ void probe_kernel(const void* __restrict__ d, int* __restrict__ flag) {
    const unsigned short* u = (const unsigned short*)d;
    const int l = threadIdx.x;   // 64
    int cnt = 0;
    for (int i = l; i < 256; i += 64) {
        const int e = (u[i] >> 7) & 0xFF;
        cnt += (e >= 118 && e <= 129) ? 1 : 0;
    }
    #pragma unroll
    for (int off = 32; off; off >>= 1) cnt += __shfl_down(cnt, off, 64);
    if (l == 0) *flag = (cnt >= 200) ? 1 : 0;   // bf16 ~255, f32 ~134
}

// ---- prep: rowsum of adj = w + I  ->  d_inv_sqrt ----
__global__ void rowsum_kernel(const void* __restrict__ w, const int* __restrict__ flagp,
                              float* __restrict__ dinv) {
    const int isbf = *flagp;
    const int i = blockIdx.x;
    const int l = threadIdx.x;
    float s = 0.f;
    for (int j = l; j < 512; j += 64) s += ldsel(w, i * 512 + j, isbf);
    #pragma unroll
    for (int off = 32; off; off >>= 1) s += __shfl_down(s, off, 64);
    if (l == 0) dinv[i] = 1.0f / sqrtf(s + 1.0f);
}

// ---- prep: fold BN -> scale/shift; canonicalize Wc, bc to f32 ----
__global__ void params_kernel(const void* g1, const void* b1, const void* m1,
                              const void* v1, const void* be1,
                              const void* g2, const void* b2, const void* m2,
                              const void* v2, const void* be2,
                              const void* Wc, const void* bc,
                              const int* __restrict__ flagp,
                              float* sc1, float* sh1, float* sc2, float* sh2,
                              float* wcf, float* bcf) {
    const int isbf = *flagp;
    const int i = threadIdx.x;  // 512
    float s1 = ldsel(g1, i, isbf) / sqrtf(ldsel(v1, i, isbf) + 1e-5f);
    sc1[i] = s1;
    sh1[i] = (ldsel(b1, i, isbf) - ldsel(m1, i, isbf)) * s1 + ldsel(be1, i, isbf);
    float s2 = ldsel(g2, i, isbf) / sqrtf(ldsel(v2, i, isbf) + 1e-5f);
    sc2[i] = s2;
    sh2[i] = (ldsel(b2, i, isbf) - ldsel(m2, i, isbf)) * s2 + ldsel(be2, i, isbf);
    wcf[i] = ldsel(Wc, i, isbf);
    wcf[512 + i] = ldsel(Wc, 512 + i, isbf);
    if (i < 2) bcf[i] = ldsel(bc, i, isbf);
}

// ---- prep: W1,W2 -> bf16 in FRAGMENT-MAJOR order.
// chunk t = ((c16*16 + kt)*64 + lane); data = W[c16*16 + (lane&15)][kt*32 + (lane>>4)*8 ..+8]
__global__ void wconv_kernel(const void* __restrict__ W1, const void* __restrict__ W2,
                             const int* __restrict__ flagp,
                             bf16_t* __restrict__ W1pk, bf16_t* __restrict__ W2pk) {
    const int isbf = *flagp;
    const int t = blockIdx.x * 256 + threadIdx.x;   // 0..32767
    const int lane = t & 63;
    const int kt = (t >> 6) & 15;
    const int c16 = t >> 10;
    const int src = (c16 * 16 + (lane & 15)) * 512 + kt * 32 + (lane >> 4) * 8;
    bf16x8 v1, v2;
    #pragma unroll
    for (int e = 0; e < 8; ++e) {
        v1[e] = (__bf16)ldsel(W1, src + e, isbf);
        v2[e] = (__bf16)ldsel(W2, src + e, isbf);
    }
    *reinterpret_cast<bf16x8*>(W1pk + (size_t)t * 8) = v1;
    *reinterpret_cast<bf16x8*>(W2pk + (size_t)t * 8) = v2;
}

// ---- prep: wn_t[n][m] = w_norm[m][n] ----
__global__ void wnorm_kernel(const void* __restrict__ w, const int* __restrict__ flagp,
                             const float* __restrict__ dinv, float* __restrict__ wn_t) {
    const int isbf = *flagp;
    const int idx = blockIdx.x * 256 + threadIdx.x;   // 262144
    const int n = idx >> 9, m = idx & 511;
    float a = ldsel(w, n * 512 + m, isbf) + (m == n ? 1.0f : 0.0f);
    wn_t[idx] = a * dinv[m] * dinv[n];
}

#define FJSTRIDE 16384   // fragment-major: 16-row-group stride (bytes)
#define FKSTRIDE 1024    // fragment-major: kt stride (bytes)

#define LOADF4(dst, base, kt)                                                  \
    _Pragma("unroll")                                                          \
    for (int q = 0; q < 4; ++q)                                                \
        dst[q] = *reinterpret_cast<const bf16x8*>((base) + q * FJSTRIDE + (kt) * FKSTRIDE);

#define MFMA16(bset, aset)                                                     \
    _Pragma("unroll")                                                          \
    for (int j = 0; j < 4; ++j)                                                \
        _Pragma("unroll")                                                      \
        for (int i = 0; i < 4; ++i)                                            \
            acc[j][i] = __builtin_amdgcn_mfma_f32_16x16x32_bf16(bset[j], aset[i], acc[j][i], 0, 0, 0);

// ---- GEMM layer (template): 256 threads = 2x2 waves, tile 128x128, BK=32.
// LAYER 1: A = raw d (f32/bf16) staged via dbuf LDS; out = T1fm (fragment-major).
// LAYER 2: A = T1fm (fragment-major, global->reg, NO barriers); out = U (atomic).
template <int LAYER>
__launch_bounds__(256, 3)
__global__ void gemm_mlp(const void* __restrict__ A,       // L1 only
                         bf16_t* __restrict__ T1fm,        // L1 out / L2 in
                         const bf16_t* __restrict__ Wpk,   // fragment-major
                         const float* __restrict__ sc, const float* __restrict__ sh,
                         const float* __restrict__ wcf,    // L2 only
                         const int* __restrict__ flagp,
                         float* __restrict__ U)            // L2 only
{
    __shared__ __align__(16) bf16_t Asg[2][128 * 32];   // 2 x 8 KB (L1)
    __shared__ float Ured[2][128][2];                   // 2 KB (L2)

    const int tid = threadIdx.x;
    const int wave = tid >> 6, lane = tid & 63;
    const int wr = wave >> 1, wc = wave & 1;   // wave tile: rows wr*64, cols wc*64
    const int rl = lane & 15, hi = lane >> 4;
    const int bn = blockIdx.x;                 // 0..3 (fast: col-blocks share A rows)
    const int bm = blockIdx.y;                 // 0..511

    // W fragment base: col-group c16 = bn*8 + wc*4 + j
    const char* wbase = (const char*)Wpk
        + ((size_t)(bn * 8 + wc * 4) * 16 * 64 + lane) * 16;

    f32x4 acc[4][4] = {};   // [j = col-frag][i = row-frag]

    if (LAYER == 1) {
        const int isbf = *flagp;
        // staging: thread t covers row t>>1, floats (t&1)*16 .. +16 of the k-tile
        const int st_r = tid >> 1;
        const int st_cf = (tid & 1) * 16;
        const size_t sgbase = (size_t)(bm * 128 + st_r) * KDIM + st_cf;
        const int sldsbase = (st_r >> 4) * 1024 + ((st_r & 15) + (st_cf >> 3) * 16) * 16;

        f32x4 s0, s1, s2, s3;
        bf16x8 sb0, sb1;

        #define SLOAD(kt)                                                      \
            if (isbf) {                                                        \
                sb0 = *reinterpret_cast<const bf16x8*>((const bf16_t*)A + sgbase + (size_t)(kt) * 32);     \
                sb1 = *reinterpret_cast<const bf16x8*>((const bf16_t*)A + sgbase + (size_t)(kt) * 32 + 8); \
            } else {                                                           \
                const f32x4* p_ = (const f32x4*)((const float*)A + sgbase + (size_t)(kt) * 32); \
                s0 = p_[0]; s1 = p_[1]; s2 = p_[2]; s3 = p_[3];                \
            }

        #define SWRITE(buf)                                                    \
            {                                                                  \
                bf16x8 v0_, v1_;                                               \
                if (isbf) { v0_ = sb0; v1_ = sb1; }                            \
                else {                                                         \
                    v0_[0]=(__bf16)s0.x; v0_[1]=(__bf16)s0.y; v0_[2]=(__bf16)s0.z; v0_[3]=(__bf16)s0.w; \
                    v0_[4]=(__bf16)s1.x; v0_[5]=(__bf16)s1.y; v0_[6]=(__bf16)s1.z; v0_[7]=(__bf16)s1.w; \
                    v1_[0]=(__bf16)s2.x; v1_[1]=(__bf16)s2.y; v1_[2]=(__bf16)s2.z; v1_[3]=(__bf16)s2.w; \
                    v1_[4]=(__bf16)s3.x; v1_[5]=(__bf16)s3.y; v1_[6]=(__bf16)s3.z; v1_[7]=(__bf16)s3.w; \
                }                                                              \
                *reinterpret_cast<bf16x8*>((char*)Asg[buf] + sldsbase)       = v0_; \
                *reinterpret_cast<bf16x8*>((char*)Asg[buf] + sldsbase + 256) = v1_; \
            }

        SLOAD(0);
        SWRITE(0);
        SLOAD(1);
        __syncthreads();

        #pragma unroll 1
        for (int kt = 0; kt < 16; ++kt) {
            bf16x8 bW[4], aT[4];
            LOADF4(bW, wbase, kt);
            #pragma unroll
            for (int i = 0; i < 4; ++i)
                aT[i] = *reinterpret_cast<const bf16x8*>(
                    (const char*)Asg[kt & 1] + (wr * 4 + i) * 1024 + lane * 16);
            MFMA16(bW, aT);
            if (kt + 1 < 16) SWRITE((kt + 1) & 1);
            if (kt + 2 < 16) SLOAD(kt + 2);
            __syncthreads();
        }
        #undef SLOAD
        #undef SWRITE

        // epilogue: BN + LReLU -> T1fm fragment-major (coalesced 8-B stores,
        // 64 lanes cover a contiguous 512-B span per (j,i))
        #pragma unroll
        for (int j = 0; j < 4; ++j) {
            const int col0 = bn * 128 + wc * 64 + j * 16 + hi * 4;
            const f32x4 s4 = *reinterpret_cast<const f32x4*>(&sc[col0]);
            const f32x4 h4 = *reinterpret_cast<const f32x4*>(&sh[col0]);
            const int kt2 = bn * 4 + wc * 2 + (j >> 1);
            const int c8 = ((j & 1) << 1) + (hi >> 1);
            #pragma unroll
            for (int i = 0; i < 4; ++i) {
                const int g = bm * 8 + wr * 4 + i;
                bf16x4 pk;
                #pragma unroll
                for (int r = 0; r < 4; ++r) {
                    float y = acc[j][i][r] * s4[r] + h4[r];
                    y = y > 0.f ? y : 0.1f * y;
                    pk[r] = (__bf16)y;
                }
                const size_t chunk = (size_t)(g * 16 + kt2) * 64 + rl + c8 * 16;
                *reinterpret_cast<bf16x4*>((char*)T1fm + chunk * 16 + (hi & 1) * 8) = pk;
            }
        }
    } else {
        // ---- LAYER 2: both operands fragment-major global->reg, no barriers ----
        const char* abase = (const char*)T1fm
            + ((size_t)(bm * 8 + wr * 4) * 16 * 64 + lane) * 16;

        bf16x8 bW0[4], bW1[4], aT0[4], aT1[4];
        LOADF4(bW0, wbase, 0);
        LOADF4(aT0, abase, 0);
        #pragma unroll 1
        for (int kt = 0; kt < 16; kt += 2) {
            LOADF4(bW1, wbase, kt + 1);
            LOADF4(aT1, abase, kt + 1);
            MFMA16(bW0, aT0);
            if (kt + 2 < 16) { LOADF4(bW0, wbase, kt + 2); LOADF4(aT0, abase, kt + 2); }
            MFMA16(bW1, aT1);
        }

        // epilogue: BN + LReLU + 512->2 projection; reduce hi via shfl, waves via LDS
        float p0[4] = {0.f, 0.f, 0.f, 0.f}, p1[4] = {0.f, 0.f, 0.f, 0.f};
        #pragma unroll
        for (int j = 0; j < 4; ++j) {
            const int col0 = bn * 128 + wc * 64 + j * 16 + hi * 4;
            const f32x4 s4 = *reinterpret_cast<const f32x4*>(&sc[col0]);
            const f32x4 h4 = *reinterpret_cast<const f32x4*>(&sh[col0]);
            const f32x4 w0 = *reinterpret_cast<const f32x4*>(&wcf[col0]);
            const f32x4 w1 = *reinterpret_cast<const f32x4*>(&wcf[512 + col0]);
            #pragma unroll
            for (int i = 0; i < 4; ++i)
                #pragma unroll
                for (int r = 0; r < 4; ++r) {
                    float y = acc[j][i][r] * s4[r] + h4[r];
                    y = y > 0.f ? y : 0.1f * y;
                    p0[i] += y * w0[r];
                    p1[i] += y * w1[r];
                }
        }
        #pragma unroll
        for (int i = 0; i < 4; ++i) {
            float a = p0[i], b = p1[i];
            a += __shfl_xor(a, 16, 64);  b += __shfl_xor(b, 16, 64);
            a += __shfl_xor(a, 32, 64);  b += __shfl_xor(b, 32, 64);
            if (hi == 0) {
                const int row = wr * 64 + i * 16 + rl;
                Ured[wc][row][0] = a;
                Ured[wc][row][1] = b;
            }
        }
        __syncthreads();
        {
            const int row = tid >> 1, c = tid & 1;
            atomicAdd(&U[(size_t)(bm * 128 + row) * 2 + c],
                      Ured[0][row][c] + Ured[1][row][c]);
        }
    }
}

// ---- GCN on 2-wide features ----
__global__ void gcn_kernel(const float* __restrict__ wn_t, const float* __restrict__ U,
                           const float* __restrict__ bcf, const int* __restrict__ flagp,
                           void* __restrict__ out) {
    const int isbf = *flagp;
    const int wave = threadIdx.x >> 6, lane = threadIdx.x & 63;
    const int task = blockIdx.x * 4 + wave;   // (b, n)
    const int b = task >> 9, n = task & 511;
    const float* wrow = wn_t + n * 512;
    const float* ub = U + b * 1024;
    float a0 = 0.f, a1 = 0.f;
    for (int m = lane; m < 512; m += 64) {
        const float wv = wrow[m];
        a0 += wv * ub[m * 2];
        a1 += wv * ub[m * 2 + 1];
    }
    #pragma unroll
    for (int off = 32; off; off >>= 1) {
        a0 += __shfl_down(a0, off, 64);
        a1 += __shfl_down(a1, off, 64);
    }
    if (lane == 0) {
        const float r0 = a0 + bcf[0];
        const float r1 = a1 + bcf[1];
        if (isbf) {
            ((bf16_t*)out)[task * 2]     = __float2bfloat16(r0);
            ((bf16_t*)out)[task * 2 + 1] = __float2bfloat16(r1);
        } else {
            ((float*)out)[task * 2]     = r0;
            ((float*)out)[task * 2 + 1] = r1;
        }
    }
}

extern "C" void kernel_launch(void* const* d_in, const int* in_sizes, int n_in,
                              void* d_out, int out_size, void* d_ws, size_t ws_size,
                              hipStream_t stream) {
    const void* d   = d_in[0];
    const void* w   = d_in[1];
    const void* W1  = d_in[2];
    const void* b1  = d_in[3];
    const void* g1  = d_in[4];
    const void* be1 = d_in[5];
    const void* m1  = d_in[6];
    const void* v1  = d_in[7];
    const void* W2  = d_in[8];
    const void* b2  = d_in[9];
    const void* g2  = d_in[10];
    const void* be2 = d_in[11];
    const void* m2  = d_in[12];
    const void* v2  = d_in[13];
    const void* Wc  = d_in[14];
    const void* bc  = d_in[15];

    // workspace layout: 3 MB small buffers + 64 MB T1fm
    char* ws = (char*)d_ws;
    float*  wn_t = (float*)ws;                         // 1 MB
    bf16_t* W1pk = (bf16_t*)(ws + 0x100000);           // 512 KB (fragment-major)
    bf16_t* W2pk = (bf16_t*)(ws + 0x180000);           // 512 KB
    float*  sc1  = (float*)(ws + 0x200000);
    float*  sh1  = sc1 + 512;
    float*  sc2  = sh1 + 512;
    float*  sh2  = sc2 + 512;
    float*  dinv = sh2 + 512;
    float*  wcf  = (float*)(ws + 0x204000);            // 4 KB
    float*  bcf  = (float*)(ws + 0x205000);
    int*    flag = (int*)(ws + 0x205100);
    float*  U    = (float*)(ws + 0x208000);            // 512 KB
    bf16_t* T1fm = (bf16_t*)(ws + 0x300000);           // 64 MB (fragment-major T1)

    const int M = 128 * 512;   // 65536 rows

    probe_kernel<<<1, 64, 0, stream>>>(d, flag);
    rowsum_kernel<<<512, 64, 0, stream>>>(w, flag, dinv);
    params_kernel<<<1, 512, 0, stream>>>(g1, b1, m1, v1, be1, g2, b2, m2, v2, be2,
                                         Wc, bc, flag, sc1, sh1, sc2, sh2, wcf, bcf);
    wconv_kernel<<<128, 256, 0, stream>>>(W1, W2, flag, W1pk, W2pk);
    wnorm_kernel<<<1024, 256, 0, stream>>>(w, flag, dinv, wn_t);

    gemm_mlp<1><<<dim3(4, M / 128), 256, 0, stream>>>(d, T1fm, W1pk, sc1, sh1,
                                                      nullptr, flag, nullptr);

    hipMemsetAsync(U, 0, (size_t)M * 2 * sizeof(float), stream);

    gemm_mlp<2><<<dim3(4, M / 128), 256, 0, stream>>>(nullptr, T1fm, W2pk, sc2, sh2,
                                                      wcf, flag, U);

    gcn_kernel<<<M / 4, 256, 0, stream>>>(wn_t, U, bcf, flag, d_out);
}